// Round 9
// baseline (978.790 us; speedup 1.0000x reference)
//
#include <hip/hip_runtime.h>
#include <stdint.h>

#define CB 32
#define CT 512
#define CK 256
#define NC 4                      // chains per block
#define NBLK (CB / NC)            // 8 blocks

typedef _Float16 half2_t __attribute__((ext_vector_type(2)));

__device__ inline float dot2f(half2_t a, half2_t b, float c) {
#if __has_builtin(__builtin_amdgcn_fdot2)
    return __builtin_amdgcn_fdot2(a, b, c, false);
#else
    asm("v_dot2_f32_f16 %0, %1, %2, %0" : "+v"(c) : "v"(a), "v"(b));
    return c;
#endif
}

__device__ inline half2_t bch2(float f) { return __builtin_bit_cast(half2_t, f); }
__device__ inline half2_t bch2u(uint32_t u) { return __builtin_bit_cast(half2_t, u); }

__device__ inline uint32_t pk2(float a, float b) {
    return __builtin_bit_cast(uint32_t,
        __builtin_amdgcn_cvt_pkrtz(__expf(a), __expf(b)));
}

// Barrier that drains LDS ops but leaves global-load (vmcnt) prefetches in flight.
__device__ inline void lds_barrier() {
    asm volatile("s_waitcnt lgkmcnt(0)\n\ts_barrier" ::: "memory");
}

// E var (i,c): rows rowbase+8i .. rowbase+8i+7, column col0+c (4 half2 row-pairs).
#define MKE(i, c) uint4 E_##i##_##c; {                                      \
    const float* tp = trans + (size_t)(rowbase + (i) * 8) * CK + (col0 + (c)); \
    E_##i##_##c.x = pk2(tp[0],      tp[CK]);                                \
    E_##i##_##c.y = pk2(tp[2 * CK], tp[3 * CK]);                            \
    E_##i##_##c.z = pk2(tp[4 * CK], tp[5 * CK]);                            \
    E_##i##_##c.w = pk2(tp[6 * CK], tp[7 * CK]); }

#define DOT4(i, qm, m, A) {                                                 \
    A##0 = dot2f(qm, bch2u(E_##i##_0.m), A##0);                             \
    A##1 = dot2f(qm, bch2u(E_##i##_1.m), A##1);                             \
    A##2 = dot2f(qm, bch2u(E_##i##_2.m), A##2);                             \
    A##3 = dot2f(qm, bch2u(E_##i##_3.m), A##3); }

// One broadcast 8-value p-chunk of chain ch dotted against E chunk i -> acc set A.
#define DOTCHUNK(i, ch, A) {                                                \
    const float4 q = *reinterpret_cast<const float4*>(&pbuf[ch][rowbase + (i) * 8]); \
    DOT4(i, bch2(q.x), x, A)                                                \
    DOT4(i, bch2(q.y), y, A)                                                \
    DOT4(i, bch2(q.z), z, A)                                                \
    DOT4(i, bch2(q.w), w, A) }

// Full 32-row x 4-col partial dot for chain ch -> float4 into sbuf[ch][q].
#define CHAINDOT(ch) {                                                      \
    float s0 = 0.f, s1 = 0.f, s2 = 0.f, s3 = 0.f;                           \
    DOTCHUNK(0, ch, s) DOTCHUNK(1, ch, s)                                   \
    DOTCHUNK(2, ch, s) DOTCHUNK(3, ch, s)                                   \
    *reinterpret_cast<float4*>(&sbuf[ch][q][col0]) = make_float4(s0, s1, s2, s3); }

// 512 threads, NC=4 chains per block. E shared across chains (same trans).
// Thread t: rowchunk q=t>>6, cols col0=(t&63)*4 for phase B (all 4 chains);
// alpha owner of states j=t&255 for chains cpair,cpair+1 where cpair=(t>>8)*2.
__global__ __launch_bounds__(512, 2) void crf_chain_kernel(
    const float* __restrict__ emissions,    // [B,T,K]
    const int* __restrict__ tags,           // [B,T]
    const int* __restrict__ mask,           // [B,T] (bool -> int32)
    const float* __restrict__ trans,        // [K,K]
    float* __restrict__ ws)                 // ws[0..31]=log_den, ws[32..63]=log_num
{
    const int chain0 = blockIdx.x * NC;
    const int tid = threadIdx.x;
    const int q = tid >> 6;                  // rowchunk, wave-uniform
    const int rowbase = q * 32;
    const int col0 = (tid & 63) * 4;
    const int j = tid & (CK - 1);            // owned state index
    const int cpair = (tid >> 8) * 2;        // first owned chain (0 or 2)
    const int wid = tid >> 6;
    const int w4 = wid & 3;                  // wave index within alpha group
    const int lane = tid & 63;

    __shared__ __align__(16) _Float16 pbuf[NC][CK];
    __shared__ __align__(16) float wmax[NC][4];
    __shared__ __align__(16) float sbuf[NC][8][CK];
    __shared__ float mask_lds[NC][CT];
    __shared__ float red[NC][4];
    __shared__ float red2[NC][4];

    // ---------------- numerator + mask staging (one t per thread) ----------------
    #pragma unroll
    for (int c = 0; c < NC; ++c) {
        const float* emC = emissions + (size_t)(chain0 + c) * CT * CK;
        const int* tagC = tags + (chain0 + c) * CT;
        const int* maskC = mask + (chain0 + c) * CT;
        const int t = tid;
        float mf = maskC[t] ? 1.f : 0.f;
        float num = emC[(size_t)t * CK + tagC[t]] * mf;
        if (t >= 1) num += trans[(size_t)tagC[t - 1] * CK + tagC[t]] * mf;
        #pragma unroll
        for (int off = 32; off > 0; off >>= 1) num += __shfl_down(num, off, 64);
        if (lane == 0) red[c][0] = 0.f;      // init below properly
        mask_lds[c][tid] = mf;
        // stash per-wave numerator partial via atomic-free two-phase: use red2 later
        if (lane == 0) red2[c][0] = 0.f;
        // store per-wave partial in sbuf scratch (free before loop)
        if (lane == 0) sbuf[c][0][wid] = num;
    }
    __syncthreads();
    if (tid < NC) {
        float s = 0.f;
        #pragma unroll
        for (int w = 0; w < 8; ++w) s += sbuf[tid][0][w];
        ws[CB + chain0 + tid] = s;
    }

    // ------------- E block: 16 named uint4 = 64 VGPRs (shared across chains) -------------
    MKE(0,0) MKE(0,1) MKE(0,2) MKE(0,3)
    MKE(1,0) MKE(1,1) MKE(1,2) MKE(1,3)
    MKE(2,0) MKE(2,1) MKE(2,2) MKE(2,3)
    MKE(3,0) MKE(3,1) MKE(3,2) MKE(3,3)
    __syncthreads();

    // ---------------- forward recursion ----------------
    const float* emA = emissions + (size_t)(chain0 + cpair) * CT * CK;
    const float* emBp = emissions + (size_t)(chain0 + cpair + 1) * CT * CK;
    float aj0 = emA[j],  emit_n0 = emA[CK + j];
    float aj1 = emBp[j], emit_n1 = emBp[CK + j];

    for (int t = 1; t < CT; ++t) {
        const float emit_t0 = emit_n0, emit_t1 = emit_n1;
        const int nxt = (t + 1 < CT) ? (t + 1) : (CT - 1);
        emit_n0 = emA[(size_t)nxt * CK + j];     // stay in flight across barriers
        emit_n1 = emBp[(size_t)nxt * CK + j];

        // phase A: two independent wave-max chains (pipeline), publish p as f16
        float m0 = aj0, m1 = aj1;
        #pragma unroll
        for (int off = 1; off < 64; off <<= 1) {
            m0 = fmaxf(m0, __shfl_xor(m0, off, 64));
            m1 = fmaxf(m1, __shfl_xor(m1, off, 64));
        }
        if (lane == 0) { wmax[cpair][w4] = m0; wmax[cpair + 1][w4] = m1; }
        pbuf[cpair][j]     = (_Float16)__expf(aj0 - m0);
        pbuf[cpair + 1][j] = (_Float16)__expf(aj1 - m1);
        lds_barrier();

        // phase B: all 4 chains' partial dots (16 independent accumulator chains)
        CHAINDOT(0) CHAINDOT(1) CHAINDOT(2) CHAINDOT(3)

        // scales for my two owned chains (consume wmax before next overwrite)
        const float4 wmA = *reinterpret_cast<const float4*>(wmax[cpair]);
        const float4 wmB = *reinterpret_cast<const float4*>(wmax[cpair + 1]);
        const float MA = fmaxf(fmaxf(wmA.x, wmA.y), fmaxf(wmA.z, wmA.w));
        const float MB = fmaxf(fmaxf(wmB.x, wmB.y), fmaxf(wmB.z, wmB.w));
        const float fA0 = __expf(wmA.x - MA), fA1 = __expf(wmA.y - MA);
        const float fA2 = __expf(wmA.z - MA), fA3 = __expf(wmA.w - MA);
        const float fB0 = __expf(wmB.x - MB), fB1 = __expf(wmB.y - MB);
        const float fB2 = __expf(wmB.z - MB), fB3 = __expf(wmB.w - MB);
        lds_barrier();

        // phase C: combine 8 rowchunk partials for each owned chain
        {
            const int cA = cpair, cB2 = cpair + 1;
            float sA = fA0 * (sbuf[cA][0][j] + sbuf[cA][1][j]);
            sA = fmaf(fA1, sbuf[cA][2][j] + sbuf[cA][3][j], sA);
            sA = fmaf(fA2, sbuf[cA][4][j] + sbuf[cA][5][j], sA);
            sA = fmaf(fA3, sbuf[cA][6][j] + sbuf[cA][7][j], sA);
            float sB = fB0 * (sbuf[cB2][0][j] + sbuf[cB2][1][j]);
            sB = fmaf(fB1, sbuf[cB2][2][j] + sbuf[cB2][3][j], sB);
            sB = fmaf(fB2, sbuf[cB2][4][j] + sbuf[cB2][5][j], sB);
            sB = fmaf(fB3, sbuf[cB2][6][j] + sbuf[cB2][7][j], sB);
            const float anA = MA + __logf(sA) + emit_t0;
            const float anB = MB + __logf(sB) + emit_t1;
            aj0 = (mask_lds[cpair][t]     != 0.f) ? anA : aj0;
            aj1 = (mask_lds[cpair + 1][t] != 0.f) ? anB : aj1;
        }
        // sbuf reads precede next bar1; next sbuf writes follow it.
    }

    // ---------------- final logsumexp per owned chain ----------------
    {
        float mx0 = aj0, mx1 = aj1;
        #pragma unroll
        for (int off = 32; off > 0; off >>= 1) {
            mx0 = fmaxf(mx0, __shfl_down(mx0, off, 64));
            mx1 = fmaxf(mx1, __shfl_down(mx1, off, 64));
        }
        if (lane == 0) { red[cpair][w4] = mx0; red[cpair + 1][w4] = mx1; }
    }
    __syncthreads();
    {
        const float g0 = fmaxf(fmaxf(red[cpair][0], red[cpair][1]),
                               fmaxf(red[cpair][2], red[cpair][3]));
        const float g1 = fmaxf(fmaxf(red[cpair + 1][0], red[cpair + 1][1]),
                               fmaxf(red[cpair + 1][2], red[cpair + 1][3]));
        float e0 = __expf(aj0 - g0), e1 = __expf(aj1 - g1);
        #pragma unroll
        for (int off = 32; off > 0; off >>= 1) {
            e0 += __shfl_down(e0, off, 64);
            e1 += __shfl_down(e1, off, 64);
        }
        if (lane == 0) { red2[cpair][w4] = e0; red2[cpair + 1][w4] = e1; }
    }
    __syncthreads();
    if (tid < NC) {
        const int c = tid;
        const float g = fmaxf(fmaxf(red[c][0], red[c][1]), fmaxf(red[c][2], red[c][3]));
        ws[chain0 + c] = g + __logf(red2[c][0] + red2[c][1] + red2[c][2] + red2[c][3]);
    }
}

__global__ void crf_finalize_kernel(const float* __restrict__ ws,
                                    float* __restrict__ out) {
    float v = 0.f;
    if ((int)threadIdx.x < CB) v = ws[threadIdx.x] - ws[CB + threadIdx.x];
    #pragma unroll
    for (int off = 32; off > 0; off >>= 1) v += __shfl_down(v, off, 64);
    if (threadIdx.x == 0) out[0] = v * (1.f / CB);
}

extern "C" void kernel_launch(void* const* d_in, const int* in_sizes, int n_in,
                              void* d_out, int out_size, void* d_ws, size_t ws_size,
                              hipStream_t stream) {
    const float* emissions = (const float*)d_in[0];
    const int* tags = (const int*)d_in[1];
    const int* mask = (const int*)d_in[2];
    const float* trans = (const float*)d_in[3];
    float* out = (float*)d_out;
    float* ws = (float*)d_ws;

    crf_chain_kernel<<<NBLK, 512, 0, stream>>>(emissions, tags, mask, trans, ws);
    crf_finalize_kernel<<<1, 64, 0, stream>>>(ws, out);
}

// Round 10
// 232.456 us; speedup vs baseline: 4.2106x; 4.2106x over previous
//
#include <hip/hip_runtime.h>
#include <stdint.h>

#define CB 32
#define CT 512
#define CK 256
#define TMID 256    // fwd produces alpha_{TMID-1}; bwd produces beta_{TMID-1}

typedef _Float16 half2_t __attribute__((ext_vector_type(2)));

__device__ inline float dot2f(half2_t a, half2_t b, float c) {
#if __has_builtin(__builtin_amdgcn_fdot2)
    return __builtin_amdgcn_fdot2(a, b, c, false);
#else
    asm("v_dot2_f32_f16 %0, %1, %2, %0" : "+v"(c) : "v"(a), "v"(b));
    return c;
#endif
}

__device__ inline half2_t bch2(float f) { return __builtin_bit_cast(half2_t, f); }
__device__ inline half2_t bch2u(uint32_t u) { return __builtin_bit_cast(half2_t, u); }

__device__ inline uint32_t pk2(float a, float b) {
    return __builtin_bit_cast(uint32_t,
        __builtin_amdgcn_cvt_pkrtz(__expf(a), __expf(b)));
}

// Barrier that drains LDS ops but leaves global-load (vmcnt) prefetches in flight.
__device__ inline void lds_barrier() {
    asm volatile("s_waitcnt lgkmcnt(0)\n\ts_barrier" ::: "memory");
}

// FWD E var (n,c): contraction rows rowbase+8n.., output column col0+c (strided).
#define MKE_F(n, c) uint4 E_##n##_##c; {                                    \
    const float* tp = trans + (size_t)(rowbase + (n) * 8) * CK + (col0 + (c)); \
    E_##n##_##c.x = pk2(tp[0],      tp[CK]);                                \
    E_##n##_##c.y = pk2(tp[2 * CK], tp[3 * CK]);                            \
    E_##n##_##c.z = pk2(tp[4 * CK], tp[5 * CK]);                            \
    E_##n##_##c.w = pk2(tp[6 * CK], tp[7 * CK]); }

// BWD E var (n,c): output row col0+c, contraction cols rowbase+8n.. (contiguous).
#define MKE_B(n, c) uint4 E_##n##_##c; {                                    \
    const float* tp = trans + (size_t)(col0 + (c)) * CK + (rowbase + (n) * 8); \
    E_##n##_##c.x = pk2(tp[0], tp[1]);                                      \
    E_##n##_##c.y = pk2(tp[2], tp[3]);                                      \
    E_##n##_##c.z = pk2(tp[4], tp[5]);                                      \
    E_##n##_##c.w = pk2(tp[6], tp[7]); }

#define DOT4(i, qm, m) {                                                    \
    acc0 = dot2f(qm, bch2u(E_##i##_0.m), acc0);                             \
    acc1 = dot2f(qm, bch2u(E_##i##_1.m), acc1);                             \
    acc2 = dot2f(qm, bch2u(E_##i##_2.m), acc2);                             \
    acc3 = dot2f(qm, bch2u(E_##i##_3.m), acc3); }

#define DOTCHUNK(i) {                                                       \
    const float4 qv = *reinterpret_cast<const float4*>(&pbuf[rowbase + (i) * 8]); \
    DOT4(i, bch2(qv.x), x)                                                  \
    DOT4(i, bch2(qv.y), y)                                                  \
    DOT4(i, bch2(qv.z), z)                                                  \
    DOT4(i, bch2(qv.w), w) }

// ws layout (floats): [0..31] logZ | [32..63] numerator |
//   [64 .. 64+32*256) alpha_mid | [64+8192 .. 64+16384) beta_mid
__global__ __launch_bounds__(512, 2) void crf_main_kernel(
    const float* __restrict__ emissions,    // [B,T,K]
    const int* __restrict__ tags,           // [B,T]
    const int* __restrict__ mask,           // [B,T] (bool -> int32)
    const float* __restrict__ trans,        // [K,K]
    float* __restrict__ ws)
{
    const int tid = threadIdx.x;
    const int q = tid >> 6;                  // rowchunk (contraction), wave-uniform
    const int rowbase = q * 32;
    const int col0 = (tid & 63) * 4;         // 4 owned output states in phase B
    const int j = tid & (CK - 1);            // owned state index (tid < CK)
    const int wid = tid >> 6;
    const int lane = tid & 63;

    __shared__ __align__(16) _Float16 pbuf[CK];
    __shared__ __align__(16) float wmax[4];
    __shared__ __align__(16) float sbuf[8][CK];
    __shared__ float mask_lds[CT];
    __shared__ float red[8];

    if (blockIdx.x < CB) {
        // ======================= FORWARD (alpha) =======================
        const int b = blockIdx.x;
        const float* emB = emissions + (size_t)b * CT * CK;
        const int* tagB = tags + b * CT;
        const int* maskB = mask + b * CT;

        // numerator (one t per thread; CT == 512) + mask staging
        {
            const int t = tid;
            float mf = maskB[t] ? 1.f : 0.f;
            float num = emB[(size_t)t * CK + tagB[t]] * mf;
            if (t >= 1) num += trans[(size_t)tagB[t - 1] * CK + tagB[t]] * mf;
            #pragma unroll
            for (int off = 32; off > 0; off >>= 1) num += __shfl_down(num, off, 64);
            if (lane == 0) red[wid] = num;
            mask_lds[tid] = mf;
            __syncthreads();
            if (tid == 0) {
                float s = 0.f;
                #pragma unroll
                for (int w = 0; w < 8; ++w) s += red[w];
                ws[CB + b] = s;
            }
        }

        MKE_F(0,0) MKE_F(0,1) MKE_F(0,2) MKE_F(0,3)
        MKE_F(1,0) MKE_F(1,1) MKE_F(1,2) MKE_F(1,3)
        MKE_F(2,0) MKE_F(2,1) MKE_F(2,2) MKE_F(2,3)
        MKE_F(3,0) MKE_F(3,1) MKE_F(3,2) MKE_F(3,3)
        __syncthreads();

        float aj = 0.f, emit_next = 0.f;
        if (tid < CK) { aj = emB[j]; emit_next = emB[CK + j]; }

        for (int t = 1; t < TMID; ++t) {
            const float emit_t = emit_next;
            if (tid < CK) {
                const int nxt = (t + 1 < TMID) ? (t + 1) : (TMID - 1);
                emit_next = emB[(size_t)nxt * CK + j];
                float m = aj;
                #pragma unroll
                for (int off = 1; off < 64; off <<= 1) m = fmaxf(m, __shfl_xor(m, off, 64));
                if (lane == 0) wmax[wid] = m;
                pbuf[j] = (_Float16)__expf(aj - m);
            }
            lds_barrier();

            float acc0 = 0.f, acc1 = 0.f, acc2 = 0.f, acc3 = 0.f;
            DOTCHUNK(0) DOTCHUNK(1) DOTCHUNK(2) DOTCHUNK(3)
            *reinterpret_cast<float4*>(&sbuf[q][col0]) =
                make_float4(acc0, acc1, acc2, acc3);

            float f0 = 0.f, f1 = 0.f, f2 = 0.f, f3 = 0.f, M = 0.f;
            if (tid < CK) {
                const float4 wm = *reinterpret_cast<const float4*>(wmax);
                M = fmaxf(fmaxf(wm.x, wm.y), fmaxf(wm.z, wm.w));
                f0 = __expf(wm.x - M); f1 = __expf(wm.y - M);
                f2 = __expf(wm.z - M); f3 = __expf(wm.w - M);
            }
            lds_barrier();

            if (tid < CK) {
                float s = f0 * (sbuf[0][j] + sbuf[1][j]);
                s = fmaf(f1, sbuf[2][j] + sbuf[3][j], s);
                s = fmaf(f2, sbuf[4][j] + sbuf[5][j], s);
                s = fmaf(f3, sbuf[6][j] + sbuf[7][j], s);
                const float anew = M + __logf(s) + emit_t;
                aj = (mask_lds[t] != 0.f) ? anew : aj;
            }
        }
        if (tid < CK) ws[2 * CB + b * CK + j] = aj;   // alpha_mid
    } else {
        // ======================= BACKWARD (beta) =======================
        const int b = blockIdx.x - CB;
        const float* emB = emissions + (size_t)b * CT * CK;
        const int* maskB = mask + b * CT;

        mask_lds[tid] = maskB[tid] ? 1.f : 0.f;

        MKE_B(0,0) MKE_B(0,1) MKE_B(0,2) MKE_B(0,3)
        MKE_B(1,0) MKE_B(1,1) MKE_B(1,2) MKE_B(1,3)
        MKE_B(2,0) MKE_B(2,1) MKE_B(2,2) MKE_B(2,3)
        MKE_B(3,0) MKE_B(3,1) MKE_B(3,2) MKE_B(3,3)
        __syncthreads();

        float bj = 0.f, emit_next = 0.f;
        if (tid < CK) emit_next = emB[(size_t)(CT - 1) * CK + j];

        for (int tn = CT - 1; tn >= TMID; --tn) {
            const float emit_t = emit_next;
            if (tid < CK) {
                const int nxt = (tn - 1 > TMID) ? (tn - 1) : TMID;
                emit_next = emB[(size_t)nxt * CK + j];
                float v = bj + emit_t;                 // beta + emit[tn]
                float m = v;
                #pragma unroll
                for (int off = 1; off < 64; off <<= 1) m = fmaxf(m, __shfl_xor(m, off, 64));
                if (lane == 0) wmax[wid] = m;
                pbuf[j] = (_Float16)__expf(v - m);
            }
            lds_barrier();

            float acc0 = 0.f, acc1 = 0.f, acc2 = 0.f, acc3 = 0.f;
            DOTCHUNK(0) DOTCHUNK(1) DOTCHUNK(2) DOTCHUNK(3)
            *reinterpret_cast<float4*>(&sbuf[q][col0]) =
                make_float4(acc0, acc1, acc2, acc3);

            float f0 = 0.f, f1 = 0.f, f2 = 0.f, f3 = 0.f, M = 0.f;
            if (tid < CK) {
                const float4 wm = *reinterpret_cast<const float4*>(wmax);
                M = fmaxf(fmaxf(wm.x, wm.y), fmaxf(wm.z, wm.w));
                f0 = __expf(wm.x - M); f1 = __expf(wm.y - M);
                f2 = __expf(wm.z - M); f3 = __expf(wm.w - M);
            }
            lds_barrier();

            if (tid < CK) {
                float s = f0 * (sbuf[0][j] + sbuf[1][j]);
                s = fmaf(f1, sbuf[2][j] + sbuf[3][j], s);
                s = fmaf(f2, sbuf[4][j] + sbuf[5][j], s);
                s = fmaf(f3, sbuf[6][j] + sbuf[7][j], s);
                const float bnew = M + __logf(s);
                bj = (mask_lds[tn] != 0.f) ? bnew : bj;
            }
        }
        if (tid < CK) ws[2 * CB + CB * CK + b * CK + j] = bj;   // beta_mid
    }
}

// logZ_b = LSE_j(alpha_mid[b][j] + beta_mid[b][j])
__global__ void crf_combine_kernel(float* __restrict__ ws) {
    const int b = blockIdx.x;
    const int tid = threadIdx.x;                 // 256 threads, 4 waves
    const int wid = tid >> 6, lane = tid & 63;
    __shared__ float red[8];
    const float v = ws[2 * CB + b * CK + tid] + ws[2 * CB + CB * CK + b * CK + tid];
    float mx = v;
    #pragma unroll
    for (int off = 32; off > 0; off >>= 1) mx = fmaxf(mx, __shfl_down(mx, off, 64));
    mx = __shfl(mx, 0, 64);
    if (lane == 0) red[wid] = mx;
    __syncthreads();
    const float gmx = fmaxf(fmaxf(red[0], red[1]), fmaxf(red[2], red[3]));
    float ex = __expf(v - gmx);
    #pragma unroll
    for (int off = 32; off > 0; off >>= 1) ex += __shfl_down(ex, off, 64);
    if (lane == 0) red[4 + wid] = ex;
    __syncthreads();
    if (tid == 0) ws[b] = gmx + __logf(red[4] + red[5] + red[6] + red[7]);
}

__global__ void crf_finalize_kernel(const float* __restrict__ ws,
                                    float* __restrict__ out) {
    float v = 0.f;
    if ((int)threadIdx.x < CB) v = ws[threadIdx.x] - ws[CB + threadIdx.x];
    #pragma unroll
    for (int off = 32; off > 0; off >>= 1) v += __shfl_down(v, off, 64);
    if (threadIdx.x == 0) out[0] = v * (1.f / CB);
}

extern "C" void kernel_launch(void* const* d_in, const int* in_sizes, int n_in,
                              void* d_out, int out_size, void* d_ws, size_t ws_size,
                              hipStream_t stream) {
    const float* emissions = (const float*)d_in[0];
    const int* tags = (const int*)d_in[1];
    const int* mask = (const int*)d_in[2];
    const float* trans = (const float*)d_in[3];
    float* out = (float*)d_out;
    float* ws = (float*)d_ws;

    crf_main_kernel<<<2 * CB, 512, 0, stream>>>(emissions, tags, mask, trans, ws);
    crf_combine_kernel<<<CB, CK, 0, stream>>>(ws);
    crf_finalize_kernel<<<1, 64, 0, stream>>>(ws, out);
}

// Round 12
// 188.984 us; speedup vs baseline: 5.1792x; 1.2300x over previous
//
#include <hip/hip_runtime.h>
#include <stdint.h>

#define CB 32
#define CT 512
#define CK 256
#define TMID 256

typedef _Float16 f16x8 __attribute__((ext_vector_type(8)));
typedef float f32x4 __attribute__((ext_vector_type(4)));

__device__ inline uint32_t pk2(float a, float b) {
    return __builtin_bit_cast(uint32_t,
        __builtin_amdgcn_cvt_pkrtz(__expf(a), __expf(b)));
}

// Barrier draining LDS only; global prefetches stay in flight.
__device__ inline void lds_barrier() {
    asm volatile("s_waitcnt lgkmcnt(0)\n\ts_barrier" ::: "memory");
}

template <int CTRL>
__device__ inline float dpp_maxf(float x) {
    int yi = __builtin_amdgcn_update_dpp(
        __builtin_bit_cast(int, x), __builtin_bit_cast(int, x),
        CTRL, 0xF, 0xF, false);
    return fmaxf(x, __builtin_bit_cast(float, yi));
}

// Full wave64 max via DPP inclusive scan (6 VALU ops) + readlane 63.
__device__ inline float wave_max(float x) {
    x = dpp_maxf<0x111>(x);   // row_shr:1
    x = dpp_maxf<0x112>(x);   // row_shr:2
    x = dpp_maxf<0x114>(x);   // row_shr:4
    x = dpp_maxf<0x118>(x);   // row_shr:8
    x = dpp_maxf<0x142>(x);   // row_bcast:15
    x = dpp_maxf<0x143>(x);   // row_bcast:31
    return __builtin_bit_cast(float,
        __builtin_amdgcn_readlane(__builtin_bit_cast(int, x), 63));
}

// FWD B-frag (kt,n): B[k][col] = exp(trans[k][col]); lane l: col = colg + n*16,
// k = kt*32 + ko8 + e (strided rows of trans).
#define MKB_F(kt, n) f16x8 B_##kt##_##n; {                                   \
    const float* tp = trans + (size_t)((kt) * 32 + ko8) * CK + (colg + (n) * 16); \
    uint4 u_;                                                                \
    u_.x = pk2(tp[0],      tp[CK]);                                          \
    u_.y = pk2(tp[2 * CK], tp[3 * CK]);                                      \
    u_.z = pk2(tp[4 * CK], tp[5 * CK]);                                      \
    u_.w = pk2(tp[6 * CK], tp[7 * CK]);                                      \
    B_##kt##_##n = __builtin_bit_cast(f16x8, u_); }

// BWD B-frag (kt,n): B[k][col] = exp(trans[col][k]) (contiguous k).
#define MKB_B(kt, n) f16x8 B_##kt##_##n; {                                   \
    const float* tp = trans + (size_t)(colg + (n) * 16) * CK + ((kt) * 32 + ko8); \
    uint4 u_;                                                                \
    u_.x = pk2(tp[0], tp[1]);                                                \
    u_.y = pk2(tp[2], tp[3]);                                                \
    u_.z = pk2(tp[4], tp[5]);                                                \
    u_.w = pk2(tp[6], tp[7]);                                                \
    B_##kt##_##n = __builtin_bit_cast(f16x8, u_); }

#define LOADB(MK) MK(0,0) MK(0,1) MK(1,0) MK(1,1) MK(2,0) MK(2,1) MK(3,0) MK(3,1) \
                  MK(4,0) MK(4,1) MK(5,0) MK(5,1) MK(6,0) MK(6,1) MK(7,0) MK(7,1)

#define MM(kt)                                                               \
    accA = __builtin_amdgcn_mfma_f32_16x16x32_f16(a##kt##_, B_##kt##_0, accA, 0, 0, 0); \
    accB = __builtin_amdgcn_mfma_f32_16x16x32_f16(a##kt##_, B_##kt##_1, accB, 0, 0, 0);

// Read A-frags (p replicated into all 16 rows: addr depends only on l>>4),
// run the 2 independent 8-deep MFMA chains. Result: s[col] in every lane.
#define MFMA_STEP                                                            \
    f16x8 a0_ = *reinterpret_cast<const f16x8*>(pbuf + 0   + ko8);           \
    f16x8 a1_ = *reinterpret_cast<const f16x8*>(pbuf + 32  + ko8);           \
    f16x8 a2_ = *reinterpret_cast<const f16x8*>(pbuf + 64  + ko8);           \
    f16x8 a3_ = *reinterpret_cast<const f16x8*>(pbuf + 96  + ko8);           \
    f16x8 a4_ = *reinterpret_cast<const f16x8*>(pbuf + 128 + ko8);           \
    f16x8 a5_ = *reinterpret_cast<const f16x8*>(pbuf + 160 + ko8);           \
    f16x8 a6_ = *reinterpret_cast<const f16x8*>(pbuf + 192 + ko8);           \
    f16x8 a7_ = *reinterpret_cast<const f16x8*>(pbuf + 224 + ko8);           \
    f32x4 accA = {0.f, 0.f, 0.f, 0.f};                                       \
    f32x4 accB = {0.f, 0.f, 0.f, 0.f};                                       \
    MM(0) MM(1) MM(2) MM(3) MM(4) MM(5) MM(6) MM(7)

// 512 threads = 8 waves per chain-segment. Wave w owns states/cols w*32..+31
// (2 MFMA N-tiles). Lane l: state sj = w*32 + nsel*16 + (l&15).
// E resident as 16 named f16x8 B-fragments (64 VGPRs).
// ws: [0..31] logZ | [32..63] numerator | [64..) alpha_mid | [64+8192..) beta_mid
__global__ __launch_bounds__(512, 1) void crf_main_kernel(
    const float* __restrict__ emissions,    // [B,T,K]
    const int* __restrict__ tags,           // [B,T]
    const int* __restrict__ mask,           // [B,T] (bool -> int32)
    const float* __restrict__ trans,        // [K,K]
    float* __restrict__ ws)
{
    const int tid = threadIdx.x;
    const int w = tid >> 6;
    const int l = tid & 63;
    const int ko8 = ((l >> 4) & 3) * 8;      // A/B k-chunk (same formula both operands)
    const int colg = w * 32 + (l & 15);
    const int nsel = (l >> 4) & 1;
    const int sj = w * 32 + nsel * 16 + (l & 15);

    __shared__ __align__(16) _Float16 pbuf[CK];
    __shared__ __align__(16) float wmaxl[8];
    __shared__ float mask_lds[CT];
    __shared__ float red[8];

    if (blockIdx.x < CB) {
        // ======================= FORWARD (alpha) =======================
        const int b = blockIdx.x;
        const float* emB = emissions + (size_t)b * CT * CK;
        const int* tagB = tags + b * CT;
        const int* maskB = mask + b * CT;

        {   // numerator (one t per thread; CT == 512) + mask staging
            const int t = tid;
            float mf = maskB[t] ? 1.f : 0.f;
            float num = emB[(size_t)t * CK + tagB[t]] * mf;
            if (t >= 1) num += trans[(size_t)tagB[t - 1] * CK + tagB[t]] * mf;
            #pragma unroll
            for (int off = 32; off > 0; off >>= 1) num += __shfl_down(num, off, 64);
            if (l == 0) red[w] = num;
            mask_lds[tid] = mf;
            __syncthreads();
            if (tid == 0) {
                float s = 0.f;
                #pragma unroll
                for (int q = 0; q < 8; ++q) s += red[q];
                ws[CB + b] = s;
            }
        }

        LOADB(MKB_F)
        __syncthreads();

        float aj = emB[sj];
        float emit_next = emB[CK + sj];

        for (int t = 1; t < TMID; ++t) {
            const float emit_t = emit_next;
            const int nxt = (t + 1 < TMID) ? (t + 1) : (TMID - 1);
            emit_next = emB[(size_t)nxt * CK + sj];

            const float mw = wave_max(aj);
            if (l == 0) wmaxl[w] = mw;
            lds_barrier();

            const float4 wa = *reinterpret_cast<const float4*>(&wmaxl[0]);
            const float4 wb = *reinterpret_cast<const float4*>(&wmaxl[4]);
            const float M = fmaxf(fmaxf(fmaxf(wa.x, wa.y), fmaxf(wa.z, wa.w)),
                                  fmaxf(fmaxf(wb.x, wb.y), fmaxf(wb.z, wb.w)));
            const float pv = __expf(aj - M);
            if (l < 32) pbuf[w * 32 + l] = (_Float16)pv;
            lds_barrier();

            MFMA_STEP
            const float s = nsel ? accB[0] : accA[0];
            const float anew = M + __logf(s) + emit_t;
            aj = (mask_lds[t] != 0.f) ? anew : aj;
        }
        if (l < 32) ws[2 * CB + b * CK + w * 32 + l] = aj;   // alpha_mid
    } else {
        // ======================= BACKWARD (beta) =======================
        const int b = blockIdx.x - CB;
        const float* emB = emissions + (size_t)b * CT * CK;
        const int* maskB = mask + b * CT;

        mask_lds[tid] = maskB[tid] ? 1.f : 0.f;

        LOADB(MKB_B)
        __syncthreads();

        float bj = 0.f;
        float emit_next = emB[(size_t)(CT - 1) * CK + sj];

        for (int tn = CT - 1; tn >= TMID; --tn) {
            const float emit_t = emit_next;
            const int nxt = (tn - 1 > TMID) ? (tn - 1) : TMID;
            emit_next = emB[(size_t)nxt * CK + sj];

            const float v = bj + emit_t;
            const float mw = wave_max(v);
            if (l == 0) wmaxl[w] = mw;
            lds_barrier();

            const float4 wa = *reinterpret_cast<const float4*>(&wmaxl[0]);
            const float4 wb = *reinterpret_cast<const float4*>(&wmaxl[4]);
            const float M = fmaxf(fmaxf(fmaxf(wa.x, wa.y), fmaxf(wa.z, wa.w)),
                                  fmaxf(fmaxf(wb.x, wb.y), fmaxf(wb.z, wb.w)));
            const float pv = __expf(v - M);
            if (l < 32) pbuf[w * 32 + l] = (_Float16)pv;
            lds_barrier();

            MFMA_STEP
            const float s = nsel ? accB[0] : accA[0];
            const float bnew = M + __logf(s);
            bj = (mask_lds[tn] != 0.f) ? bnew : bj;
        }
        if (l < 32) ws[2 * CB + CB * CK + b * CK + w * 32 + l] = bj;   // beta_mid
    }
}

// logZ_b = LSE_j(alpha_mid[b][j] + beta_mid[b][j])
__global__ void crf_combine_kernel(float* __restrict__ ws) {
    const int b = blockIdx.x;
    const int tid = threadIdx.x;                 // 256 threads, 4 waves
    const int wid = tid >> 6, lane = tid & 63;
    __shared__ float red[8];
    const float v = ws[2 * CB + b * CK + tid] + ws[2 * CB + CB * CK + b * CK + tid];
    float mx = v;
    #pragma unroll
    for (int off = 32; off > 0; off >>= 1) mx = fmaxf(mx, __shfl_down(mx, off, 64));
    mx = __shfl(mx, 0, 64);
    if (lane == 0) red[wid] = mx;
    __syncthreads();
    const float gmx = fmaxf(fmaxf(red[0], red[1]), fmaxf(red[2], red[3]));
    float ex = __expf(v - gmx);
    #pragma unroll
    for (int off = 32; off > 0; off >>= 1) ex += __shfl_down(ex, off, 64);
    if (lane == 0) red[4 + wid] = ex;
    __syncthreads();
    if (tid == 0) ws[b] = gmx + __logf(red[4] + red[5] + red[6] + red[7]);
}

__global__ void crf_finalize_kernel(const float* __restrict__ ws,
                                    float* __restrict__ out) {
    float v = 0.f;
    if ((int)threadIdx.x < CB) v = ws[threadIdx.x] - ws[CB + threadIdx.x];
    #pragma unroll
    for (int off = 32; off > 0; off >>= 1) v += __shfl_down(v, off, 64);
    if (threadIdx.x == 0) out[0] = v * (1.f / CB);
}

extern "C" void kernel_launch(void* const* d_in, const int* in_sizes, int n_in,
                              void* d_out, int out_size, void* d_ws, size_t ws_size,
                              hipStream_t stream) {
    const float* emissions = (const float*)d_in[0];
    const int* tags = (const int*)d_in[1];
    const int* mask = (const int*)d_in[2];
    const float* trans = (const float*)d_in[3];
    float* out = (float*)d_out;
    float* ws = (float*)d_ws;

    crf_main_kernel<<<2 * CB, 512, 0, stream>>>(emissions, tags, mask, trans, ws);
    crf_combine_kernel<<<CB, CK, 0, stream>>>(ws);
    crf_finalize_kernel<<<1, 64, 0, stream>>>(ws, out);
}

// Round 13
// 159.993 us; speedup vs baseline: 6.1177x; 1.1812x over previous
//
#include <hip/hip_runtime.h>
#include <stdint.h>

#define CB 32
#define CT 512
#define CK 256
#define TMID 256
#define SHIFT 5.0f

typedef _Float16 f16x8 __attribute__((ext_vector_type(8)));
typedef float f32x4 __attribute__((ext_vector_type(4)));

__device__ inline uint32_t pk2(float a, float b) {
    return __builtin_bit_cast(uint32_t,
        __builtin_amdgcn_cvt_pkrtz(__expf(a), __expf(b)));
}

// Barrier draining LDS only; global prefetches stay in flight.
__device__ inline void lds_barrier() {
    asm volatile("s_waitcnt lgkmcnt(0)\n\ts_barrier" ::: "memory");
}

template <int CTRL>
__device__ inline float dpp_maxf(float x) {
    int yi = __builtin_amdgcn_update_dpp(
        __builtin_bit_cast(int, x), __builtin_bit_cast(int, x),
        CTRL, 0xF, 0xF, false);
    return fmaxf(x, __builtin_bit_cast(float, yi));
}

// Full wave64 max via DPP inclusive scan (6 VALU ops) + readlane 63.
__device__ inline float wave_max(float x) {
    x = dpp_maxf<0x111>(x);   // row_shr:1
    x = dpp_maxf<0x112>(x);   // row_shr:2
    x = dpp_maxf<0x114>(x);   // row_shr:4
    x = dpp_maxf<0x118>(x);   // row_shr:8
    x = dpp_maxf<0x142>(x);   // row_bcast:15
    x = dpp_maxf<0x143>(x);   // row_bcast:31
    return __builtin_bit_cast(float,
        __builtin_amdgcn_readlane(__builtin_bit_cast(int, x), 63));
}

// FWD B-frag (kt,n): B[k][col] = exp(trans[k][col]); strided rows of trans.
#define MKB_F(kt, n) f16x8 B_##kt##_##n; {                                   \
    const float* tp = trans + (size_t)((kt) * 32 + ko8) * CK + (colg + (n) * 16); \
    uint4 u_;                                                                \
    u_.x = pk2(tp[0],      tp[CK]);                                          \
    u_.y = pk2(tp[2 * CK], tp[3 * CK]);                                      \
    u_.z = pk2(tp[4 * CK], tp[5 * CK]);                                      \
    u_.w = pk2(tp[6 * CK], tp[7 * CK]);                                      \
    B_##kt##_##n = __builtin_bit_cast(f16x8, u_); }

// BWD B-frag (kt,n): B[k][col] = exp(trans[col][k]) (contiguous k).
#define MKB_B(kt, n) f16x8 B_##kt##_##n; {                                   \
    const float* tp = trans + (size_t)(colg + (n) * 16) * CK + ((kt) * 32 + ko8); \
    uint4 u_;                                                                \
    u_.x = pk2(tp[0], tp[1]);                                                \
    u_.y = pk2(tp[2], tp[3]);                                                \
    u_.z = pk2(tp[4], tp[5]);                                                \
    u_.w = pk2(tp[6], tp[7]);                                                \
    B_##kt##_##n = __builtin_bit_cast(f16x8, u_); }

#define LOADB(MK) MK(0,0) MK(0,1) MK(1,0) MK(1,1) MK(2,0) MK(2,1) MK(3,0) MK(3,1) \
                  MK(4,0) MK(4,1) MK(5,0) MK(5,1) MK(6,0) MK(6,1) MK(7,0) MK(7,1)

#define MM(kt)                                                               \
    accA = __builtin_amdgcn_mfma_f32_16x16x32_f16(a##kt##_, B_##kt##_0, accA, 0, 0, 0); \
    accB = __builtin_amdgcn_mfma_f32_16x16x32_f16(a##kt##_, B_##kt##_1, accB, 0, 0, 0);

// A-frags from pb (p replicated in all 16 rows); two 8-deep MFMA chains.
#define MFMA_STEP(pb)                                                        \
    f16x8 a0_ = *reinterpret_cast<const f16x8*>((pb) + 0   + ko8);           \
    f16x8 a1_ = *reinterpret_cast<const f16x8*>((pb) + 32  + ko8);           \
    f16x8 a2_ = *reinterpret_cast<const f16x8*>((pb) + 64  + ko8);           \
    f16x8 a3_ = *reinterpret_cast<const f16x8*>((pb) + 96  + ko8);           \
    f16x8 a4_ = *reinterpret_cast<const f16x8*>((pb) + 128 + ko8);           \
    f16x8 a5_ = *reinterpret_cast<const f16x8*>((pb) + 160 + ko8);           \
    f16x8 a6_ = *reinterpret_cast<const f16x8*>((pb) + 192 + ko8);           \
    f16x8 a7_ = *reinterpret_cast<const f16x8*>((pb) + 224 + ko8);           \
    f32x4 accA = {0.f, 0.f, 0.f, 0.f};                                       \
    f32x4 accB = {0.f, 0.f, 0.f, 0.f};                                       \
    MM(0) MM(1) MM(2) MM(3) MM(4) MM(5) MM(6) MM(7)

// 512 threads = 8 waves. Wave w owns states w*32..+31; lane l: sj = w*32+nsel*16+(l&15).
// ONE barrier/step: double-buffered pbuf/wmaxl + one-step-stale Mref (+SHIFT guard).
// ws: [0..31] logZ | [32..63] numerator | [64..) alpha_mid | [64+8192..) beta_mid
__global__ __launch_bounds__(512, 1) void crf_main_kernel(
    const float* __restrict__ emissions,    // [B,T,K]
    const int* __restrict__ tags,           // [B,T]
    const int* __restrict__ mask,           // [B,T] (bool -> int32)
    const float* __restrict__ trans,        // [K,K]
    float* __restrict__ ws)
{
    const int tid = threadIdx.x;
    const int w = tid >> 6;
    const int l = tid & 63;
    const int ko8 = ((l >> 4) & 3) * 8;
    const int colg = w * 32 + (l & 15);
    const int nsel = (l >> 4) & 1;
    const int sj = w * 32 + nsel * 16 + (l & 15);

    __shared__ __align__(16) _Float16 pbuf[2][CK];
    __shared__ __align__(16) float wmaxl[2][8];
    __shared__ float mask_lds[CT];
    __shared__ float red[8];

    if (blockIdx.x < CB) {
        // ======================= FORWARD (alpha) =======================
        const int b = blockIdx.x;
        const float* emB = emissions + (size_t)b * CT * CK;
        const int* tagB = tags + b * CT;
        const int* maskB = mask + b * CT;

        {   // numerator (one t per thread; CT == 512) + mask staging
            const int t = tid;
            float mf = maskB[t] ? 1.f : 0.f;
            float num = emB[(size_t)t * CK + tagB[t]] * mf;
            if (t >= 1) num += trans[(size_t)tagB[t - 1] * CK + tagB[t]] * mf;
            #pragma unroll
            for (int off = 32; off > 0; off >>= 1) num += __shfl_down(num, off, 64);
            if (l == 0) red[w] = num;
            mask_lds[tid] = mf;
            __syncthreads();
            if (tid == 0) {
                float s = 0.f;
                #pragma unroll
                for (int q = 0; q < 8; ++q) s += red[q];
                ws[CB + b] = s;
            }
        }

        LOADB(MKB_F)

        float aj = emB[sj];
        float emit_next = emB[CK + sj];

        // prologue: exact Mref for t=1
        {
            const float mw = wave_max(aj);
            if (l == 0) wmaxl[1][w] = mw;
        }
        __syncthreads();
        float Mref;
        {
            const float4 wa = *reinterpret_cast<const float4*>(&wmaxl[1][0]);
            const float4 wb = *reinterpret_cast<const float4*>(&wmaxl[1][4]);
            Mref = fmaxf(fmaxf(fmaxf(wa.x, wa.y), fmaxf(wa.z, wa.w)),
                         fmaxf(fmaxf(wb.x, wb.y), fmaxf(wb.z, wb.w))) + SHIFT;
        }

        for (int t = 1; t < TMID; ++t) {
            const float emit_t = emit_next;
            const int nxt = (t + 1 < TMID) ? (t + 1) : (TMID - 1);
            emit_next = emB[(size_t)nxt * CK + sj];
            const int bsel = t & 1;

            // pre-barrier: publish wave max (consumed NEXT step) + p
            const float mw = wave_max(aj);
            if (l == 0) wmaxl[bsel][w] = mw;
            const float pv = __expf(aj - Mref);
            if (l < 32) pbuf[bsel][w * 32 + l] = (_Float16)pv;
            lds_barrier();

            // post-barrier: next-step Mref (off critical path) + MFMA
            const float4 wa = *reinterpret_cast<const float4*>(&wmaxl[bsel][0]);
            const float4 wb = *reinterpret_cast<const float4*>(&wmaxl[bsel][4]);
            const float Mnext = fmaxf(fmaxf(fmaxf(wa.x, wa.y), fmaxf(wa.z, wa.w)),
                                      fmaxf(fmaxf(wb.x, wb.y), fmaxf(wb.z, wb.w))) + SHIFT;

            MFMA_STEP(pbuf[bsel])
            const float s = nsel ? accB[0] : accA[0];
            const float anew = Mref + __logf(s) + emit_t;
            aj = (mask_lds[t] != 0.f) ? anew : aj;
            Mref = Mnext;
        }
        if (l < 32) ws[2 * CB + b * CK + w * 32 + l] = aj;   // alpha_mid
    } else {
        // ======================= BACKWARD (beta) =======================
        const int b = blockIdx.x - CB;
        const float* emB = emissions + (size_t)b * CT * CK;
        const int* maskB = mask + b * CT;

        mask_lds[tid] = maskB[tid] ? 1.f : 0.f;

        LOADB(MKB_B)

        float bj = 0.f;
        float emit_next = emB[(size_t)(CT - 1) * CK + sj];
        __syncthreads();   // mask_lds ready; also covers LDS reuse

        // prologue: exact Mref for first step (v = bj + emit at tn = CT-1)
        {
            const float mw = wave_max(bj + emit_next);
            if (l == 0) wmaxl[(CT - 1) & 1][w] = mw;
        }
        __syncthreads();
        float Mref;
        {
            const int pb0 = (CT - 1) & 1;
            const float4 wa = *reinterpret_cast<const float4*>(&wmaxl[pb0][0]);
            const float4 wb = *reinterpret_cast<const float4*>(&wmaxl[pb0][4]);
            Mref = fmaxf(fmaxf(fmaxf(wa.x, wa.y), fmaxf(wa.z, wa.w)),
                         fmaxf(fmaxf(wb.x, wb.y), fmaxf(wb.z, wb.w))) + SHIFT;
        }

        for (int tn = CT - 1; tn >= TMID; --tn) {
            const float emit_t = emit_next;
            const int nxt = (tn - 1 > TMID) ? (tn - 1) : TMID;
            emit_next = emB[(size_t)nxt * CK + sj];
            const int bsel = tn & 1;

            const float v = bj + emit_t;
            const float mw = wave_max(v);
            if (l == 0) wmaxl[bsel][w] = mw;
            const float pv = __expf(v - Mref);
            if (l < 32) pbuf[bsel][w * 32 + l] = (_Float16)pv;
            lds_barrier();

            const float4 wa = *reinterpret_cast<const float4*>(&wmaxl[bsel][0]);
            const float4 wb = *reinterpret_cast<const float4*>(&wmaxl[bsel][4]);
            const float Mnext = fmaxf(fmaxf(fmaxf(wa.x, wa.y), fmaxf(wa.z, wa.w)),
                                      fmaxf(fmaxf(wb.x, wb.y), fmaxf(wb.z, wb.w))) + SHIFT;

            MFMA_STEP(pbuf[bsel])
            const float s = nsel ? accB[0] : accA[0];
            const float bnew = Mref + __logf(s);
            bj = (mask_lds[tn] != 0.f) ? bnew : bj;
            Mref = Mnext;
        }
        if (l < 32) ws[2 * CB + CB * CK + b * CK + w * 32 + l] = bj;   // beta_mid
    }
}

// logZ_b = LSE_j(alpha_mid[b][j] + beta_mid[b][j])
__global__ void crf_combine_kernel(float* __restrict__ ws) {
    const int b = blockIdx.x;
    const int tid = threadIdx.x;                 // 256 threads, 4 waves
    const int wid = tid >> 6, lane = tid & 63;
    __shared__ float red[8];
    const float v = ws[2 * CB + b * CK + tid] + ws[2 * CB + CB * CK + b * CK + tid];
    float mx = v;
    #pragma unroll
    for (int off = 32; off > 0; off >>= 1) mx = fmaxf(mx, __shfl_down(mx, off, 64));
    mx = __shfl(mx, 0, 64);
    if (lane == 0) red[wid] = mx;
    __syncthreads();
    const float gmx = fmaxf(fmaxf(red[0], red[1]), fmaxf(red[2], red[3]));
    float ex = __expf(v - gmx);
    #pragma unroll
    for (int off = 32; off > 0; off >>= 1) ex += __shfl_down(ex, off, 64);
    if (lane == 0) red[4 + wid] = ex;
    __syncthreads();
    if (tid == 0) ws[b] = gmx + __logf(red[4] + red[5] + red[6] + red[7]);
}

__global__ void crf_finalize_kernel(const float* __restrict__ ws,
                                    float* __restrict__ out) {
    float v = 0.f;
    if ((int)threadIdx.x < CB) v = ws[threadIdx.x] - ws[CB + threadIdx.x];
    #pragma unroll
    for (int off = 32; off > 0; off >>= 1) v += __shfl_down(v, off, 64);
    if (threadIdx.x == 0) out[0] = v * (1.f / CB);
}

extern "C" void kernel_launch(void* const* d_in, const int* in_sizes, int n_in,
                              void* d_out, int out_size, void* d_ws, size_t ws_size,
                              hipStream_t stream) {
    const float* emissions = (const float*)d_in[0];
    const int* tags = (const int*)d_in[1];
    const int* mask = (const int*)d_in[2];
    const float* trans = (const float*)d_in[3];
    float* out = (float*)d_out;
    float* ws = (float*)d_ws;

    crf_main_kernel<<<2 * CB, 512, 0, stream>>>(emissions, tags, mask, trans, ws);
    crf_combine_kernel<<<CB, CK, 0, stream>>>(ws);
    crf_finalize_kernel<<<1, 64, 0, stream>>>(ws, out);
}